// Round 8
// baseline (176.204 us; speedup 1.0000x reference)
//
#include <hip/hip_runtime.h>

#define T_SEQ 8192
#define E_DIM 1024
#define QS 36              // padded qkv row: [k 0..10][pad][q 12..22][pad][v 24..34][pad]
#define QNEC 16            // E-chunk grid dim (x2 32-col sub-chunks in-kernel)
#define QKC 32             // cols per qkv sub-chunk
#define QX4 8              // QKC/4 float4-cols
#define QXST 9             // padded f4 stride: 36 words = 4 mod 32 -> 2-way (free)
#define QRB 128            // qkv rows per block (2/lane)
#define AJW 16             // attn j per wave
#define ABJ 128            // attn j per block (8 waves)
#define ARB 256            // attn rows per row-group (4/lane)
#define KVW 24             // LDS kv row: [k0..10,pad][v0..10,pad]
#define TR 16              // pass2 rows per block

__device__ __forceinline__ float2 pkfma(float2 a, float2 b, float2 c) {
    return make_float2(fmaf(a.x, b.x, c.x), fmaf(a.y, b.y, c.y));
}
__device__ __forceinline__ float2 f2(float x, float y) { return make_float2(x, y); }

// pack a 6-f2 output row into 3 f4
__device__ __forceinline__ void pack3(const float2 o[6], float4* dst) {
    float4 t;
    t.x = o[0].x; t.y = o[0].y; t.z = o[1].x; t.w = o[1].y; dst[0] = t;
    t.x = o[2].x; t.y = o[2].y; t.z = o[3].x; t.w = o[3].y; dst[1] = t;
    t.x = o[4].x; t.y = o[4].y; t.z = o[5].x; t.w = o[5].y; dst[2] = t;
}

// ws floats: qkvF[T][QS] 1.18MB | region R: partQ[16][T][QS] 18.9MB overlaid
//   by part[64][T][12] 25.2MB (partQ dead after reduceQ; stream-ordered).
//   ~26.4MB total (proven-safe). NO atomics (R4: device fp atomicAdd = 32B
//   HBM write-through each, 10x cost).

// ---------------------------------------------------------------------------
// K1: qkv projection, 2 ROWS/LANE (doubles FMA per LDS broadcast vs R7's 1).
// Block 256 thr = 128 rows x 4 col-groups; 2 sub-chunks of 32 cols in-kernel.
// Per c4-iter: 2 per-lane b128 x-reads + 9 broadcast b128 w-reads -> 72 v_fma.
// LDS 23KB (xT 18.4 + wT 4.6) -> 6 blocks/CU cap; grid dim3(64,16) = 1024 =
// 4.0 blocks/CU uniform (16 waves/CU). Epilogue transposes through LDS
// (res overlays xT exactly), coalesced f4 write.
// ---------------------------------------------------------------------------
__global__ __launch_bounds__(256) void qkv_proj(
    const float* __restrict__ xe,
    const float* __restrict__ Wk, const float* __restrict__ bk,
    const float* __restrict__ Wq, const float* __restrict__ bq,
    const float* __restrict__ Wv, const float* __restrict__ bv,
    float* __restrict__ partQ) {
    const int row0 = blockIdx.x * QRB;
    const int ec = blockIdx.y;
    const int lane = threadIdx.x & 63;
    const int wg = threadIdx.x >> 6;

    __shared__ float4 xT[QRB * QXST];     // 18.4 KB
    __shared__ float4 wT[36 * QX4];       // 4.6 KB

    float2 acc[2][9];
#pragma unroll
    for (int u = 0; u < 2; ++u)
#pragma unroll
        for (int k = 0; k < 9; ++k) acc[u][k] = f2(0.f, 0.f);

    for (int cc = 0; cc < 2; ++cc) {
        const int cb = ec * 64 + cc * QKC;
        if (cc) __syncthreads();          // WAR on xT/wT

        // stage xe tile: 1024 f4, 4/thread, 8 threads per 128B row segment
#pragma unroll
        for (int t = 0; t < 4; ++t) {
            int idx = threadIdx.x + t * 256;
            int r = idx >> 3, c4 = idx & 7;
            xT[r * QXST + c4] =
                *(const float4*)(xe + (size_t)(row0 + r) * E_DIM + cb + c4 * 4);
        }
        // stage W tile: 36 rows x 8 f4 (rows 33..35 zero)
        for (int idx = threadIdx.x; idx < 36 * QX4; idx += 256) {
            int r = idx >> 3, c4 = idx & 7;
            float4 v = make_float4(0.f, 0.f, 0.f, 0.f);
            if (r < 33) {
                const float* base = (r < 11) ? (Wk + (size_t)r * E_DIM)
                                  : (r < 22) ? (Wq + (size_t)(r - 11) * E_DIM)
                                             : (Wv + (size_t)(r - 22) * E_DIM);
                v = *(const float4*)(base + cb + c4 * 4);
            }
            wT[idx] = v;
        }
        __syncthreads();

        const float4* xr = xT + lane * QXST;
        const float4* wr = wT + wg * 9 * QX4;
#pragma unroll
        for (int c4 = 0; c4 < QX4; ++c4) {
            float4 xv0 = xr[c4];
            float4 xv1 = xr[64 * QXST + c4];
#pragma unroll
            for (int k = 0; k < 9; ++k) {
                float4 wv = wr[k * QX4 + c4];          // broadcast
                float2 wlo = f2(wv.x, wv.y), whi = f2(wv.z, wv.w);
                acc[0][k] = pkfma(f2(xv0.x, xv0.y), wlo, acc[0][k]);
                acc[0][k] = pkfma(f2(xv0.z, xv0.w), whi, acc[0][k]);
                acc[1][k] = pkfma(f2(xv1.x, xv1.y), wlo, acc[1][k]);
                acc[1][k] = pkfma(f2(xv1.z, xv1.w), whi, acc[1][k]);
            }
        }
    }

    // transpose through LDS (res overlays xT exactly: 128*36 floats = 18.4KB)
    __syncthreads();
    float* res = (float*)xT;
#pragma unroll
    for (int k = 0; k < 9; ++k) {
        int o = wg * 9 + k;
        bool live = (o < 33);
        int c = (o < 11) ? o : (o < 22) ? o + 1 : (o < 33) ? o + 2
              : (o == 33) ? 11 : (o == 34) ? 23 : 35;
        float b = 0.f;
        if (ec == 0 && live)
            b = (o < 11) ? bk[o] : (o < 22) ? bq[o - 11] : bv[o - 22];
        res[lane * 36 + c]        = live ? (acc[0][k].x + acc[0][k].y + b) : 0.f;
        res[(lane + 64) * 36 + c] = live ? (acc[1][k].x + acc[1][k].y + b) : 0.f;
    }
    __syncthreads();

    // coalesced f4 write: 128 rows x 9 f4 = 1152 contiguous f4
    float4* dst = (float4*)(partQ + ((size_t)ec * T_SEQ + row0) * QS);
    for (int idx = threadIdx.x; idx < QRB * 9; idx += 256) {
        int r = idx / 9, f = idx % 9;
        dst[idx] = *(const float4*)(res + r * 36 + f * 4);
    }
}

// ---------------------------------------------------------------------------
// K2: reduce QNEC qkv partial chunks into dense qkvF. 18.9MB read, 1.2MB write.
// ---------------------------------------------------------------------------
__global__ __launch_bounds__(256) void reduceQ(const float* __restrict__ partQ,
                                               float* __restrict__ qkvF) {
    const size_t idx = (size_t)blockIdx.x * 256 + threadIdx.x;
    const float4* p = (const float4*)partQ;
    const size_t cs = (size_t)T_SEQ * (QS / 4);
    float4 s = make_float4(0.f, 0.f, 0.f, 0.f);
#pragma unroll
    for (int c = 0; c < QNEC; ++c) {
        float4 a = p[idx + (size_t)c * cs];
        s.x += a.x; s.y += a.y; s.z += a.z; s.w += a.w;
    }
    ((float4*)qkvF)[idx] = s;
}

// ---------------------------------------------------------------------------
// K3: causal attention, 8-WAVE blocks (512 thr), 4 rows/lane, 16 j/wave.
// Block b -> (rb, c): prefix(rb) = rb(rb+1), c in [0, 2rb+2) — covers 128 j.
// Wave w: j0 = c*128 + w*16. 1056 blocks x 8 = 8448 waves; LDS 48KB (kv 12KB
// + combine tree overlaid on dead kv) -> 3 blocks/CU = 24 waves/CU = 6/SIMD
// (vs R7's grid-limited 4.1/SIMD). 3-round LDS tree folds 8 waves; wave 0
// writes ONE slot c of part[64][T][12]. NO atomics.
// ---------------------------------------------------------------------------
__global__ __launch_bounds__(512) void attn(const float* __restrict__ qkvF,
                                            float* __restrict__ part) {
    const int b = blockIdx.x;
    int rb = 0;
    while ((rb + 1) * (rb + 2) <= b) ++rb;        // prefix(rb) = rb(rb+1)
    const int c = b - rb * (rb + 1);              // c in [0, 2rb+2)
    const int lane = threadIdx.x & 63;
    const int wid = threadIdx.x >> 6;
    const int r0 = rb * ARB + lane * 4;
    const int j0 = c * ABJ + wid * AJW;

    __shared__ float sh[12288];                   // 48KB: kv[8][384] | red 4x12KB
    float* kv = sh + wid * (AJW * KVW);           // wave-private 1.5KB

    // q for 4 rows, packed as 6 f2 each (pair 5 = (q10, 0))
    float2 q[4][6], o[4][6];
#pragma unroll
    for (int i = 0; i < 4; ++i) {
        const float* qp = qkvF + (size_t)(r0 + i) * QS + 12;
#pragma unroll
        for (int d = 0; d < 5; ++d) q[i][d] = f2(qp[2 * d], qp[2 * d + 1]);
        q[i][5] = f2(qp[10], 0.f);
#pragma unroll
        for (int d = 0; d < 6; ++d) o[i][d] = f2(0.f, 0.f);
    }

    // stage 16 rows x 6 f4 = 96 f4 (wave-private; within-wave lgkmcnt ordering)
#pragma unroll
    for (int t = 0; t < 2; ++t) {
        int idx = lane + t * 64;
        if (idx < AJW * 6) {
            int row = idx / 6, f = idx % 6;
            int srcOff = f * 4 + (f >= 3 ? 12 : 0);
            float4 v = *(const float4*)(qkvF + (size_t)(j0 + row) * QS + srcOff);
            *(float4*)(kv + row * KVW + f * 4) = v;
        }
    }

    for (int jj = 0; jj < AJW; ++jj) {
        const float* kp = kv + jj * KVW;
        const float4 kA = *(const float4*)(kp);
        const float4 kB = *(const float4*)(kp + 4);
        const float4 kC = *(const float4*)(kp + 8);   // .w = 0 (pad)
        const float4 vA = *(const float4*)(kp + 12);
        const float4 vB = *(const float4*)(kp + 16);
        const float4 vC = *(const float4*)(kp + 20);  // .w = 0 (pad)
        const float2 k01 = f2(kA.x, kA.y), k23 = f2(kA.z, kA.w);
        const float2 k45 = f2(kB.x, kB.y), k67 = f2(kB.z, kB.w);
        const float2 k89 = f2(kC.x, kC.y), kXp = f2(kC.z, kC.w);
        const int j = j0 + jj;

#pragma unroll
        for (int i = 0; i < 4; ++i) {
            float2 s = pkfma(q[i][0], k01, pkfma(q[i][1], k23, pkfma(q[i][2], k45,
                       pkfma(q[i][3], k67, pkfma(q[i][4], k89,
                       pkfma(q[i][5], kXp, f2(0.f, 0.f)))))));
            float pe = __expf(s.x + s.y);
            pe = (j <= r0 + i) ? pe : 0.f;
            float2 p2 = f2(pe, pe);
            o[i][0] = pkfma(p2, f2(vA.x, vA.y), o[i][0]);
            o[i][1] = pkfma(p2, f2(vA.z, vA.w), o[i][1]);
            o[i][2] = pkfma(p2, f2(vB.x, vB.y), o[i][2]);
            o[i][3] = pkfma(p2, f2(vB.z, vB.w), o[i][3]);
            o[i][4] = pkfma(p2, f2(vC.x, vC.y), o[i][4]);
            o[i][5] = pkfma(p2, f2(vC.z, 1.f),  o[i][5]);   // o10, l
        }
    }

    // 3-round tree combine in 48KB (kv dead after first barrier)
    float4* red = (float4*)sh;                    // 4 bufs x 768 f4 (12KB)
    __syncthreads();
    if (wid >= 4) {
        float4* dst = red + (size_t)(wid - 4) * 768 + lane * 12;
#pragma unroll
        for (int i = 0; i < 4; ++i) pack3(o[i], dst + i * 3);
    }
    __syncthreads();
    if (wid < 4) {
        const float4* src = red + (size_t)wid * 768 + lane * 12;
#pragma unroll
        for (int i = 0; i < 4; ++i) {
            float4 s0 = src[i * 3 + 0], s1 = src[i * 3 + 1], s2 = src[i * 3 + 2];
            o[i][0].x += s0.x; o[i][0].y += s0.y; o[i][1].x += s0.z; o[i][1].y += s0.w;
            o[i][2].x += s1.x; o[i][2].y += s1.y; o[i][3].x += s1.z; o[i][3].y += s1.w;
            o[i][4].x += s2.x; o[i][4].y += s2.y; o[i][5].x += s2.z; o[i][5].y += s2.w;
        }
    }
    __syncthreads();
    if (wid == 2 || wid == 3) {
        float4* dst = red + (size_t)(wid - 2) * 768 + lane * 12;
#pragma unroll
        for (int i = 0; i < 4; ++i) pack3(o[i], dst + i * 3);
    }
    __syncthreads();
    if (wid < 2) {
        const float4* src = red + (size_t)wid * 768 + lane * 12;
#pragma unroll
        for (int i = 0; i < 4; ++i) {
            float4 s0 = src[i * 3 + 0], s1 = src[i * 3 + 1], s2 = src[i * 3 + 2];
            o[i][0].x += s0.x; o[i][0].y += s0.y; o[i][1].x += s0.z; o[i][1].y += s0.w;
            o[i][2].x += s1.x; o[i][2].y += s1.y; o[i][3].x += s1.z; o[i][3].y += s1.w;
            o[i][4].x += s2.x; o[i][4].y += s2.y; o[i][5].x += s2.z; o[i][5].y += s2.w;
        }
    }
    __syncthreads();
    if (wid == 1) {
        float4* dst = red + lane * 12;
#pragma unroll
        for (int i = 0; i < 4; ++i) pack3(o[i], dst + i * 3);
    }
    __syncthreads();
    if (wid == 0) {
        const float4* src = red + lane * 12;
#pragma unroll
        for (int i = 0; i < 4; ++i) {
            float4 s0 = src[i * 3 + 0], s1 = src[i * 3 + 1], s2 = src[i * 3 + 2];
            o[i][0].x += s0.x; o[i][0].y += s0.y; o[i][1].x += s0.z; o[i][1].y += s0.w;
            o[i][2].x += s1.x; o[i][2].y += s1.y; o[i][3].x += s1.z; o[i][3].y += s1.w;
            o[i][4].x += s2.x; o[i][4].y += s2.y; o[i][5].x += s2.z; o[i][5].y += s2.w;
        }
        float* d0 = part + ((size_t)c * T_SEQ + r0) * 12;
#pragma unroll
        for (int i = 0; i < 4; ++i) pack3(o[i], (float4*)(d0 + i * 12));
    }
}

// ---------------------------------------------------------------------------
// K4: fused partial-reduce + normalize + output GEMM + bias. 16-way parallel
// slot reduction: 256 thr = 16 rows x 16 slot-groups, <=4 independent rounds,
// LDS tree-combine. Wf read directly (4 contiguous 11-float rows/thread,
// L3-resident). cnt for row t: 2*(t/256)+2 <= 64, uniform per block.
// ---------------------------------------------------------------------------
__global__ __launch_bounds__(256) void pass2(const float* __restrict__ part,
                                             const float* __restrict__ Wf,
                                             const float* __restrict__ bf,
                                             float* __restrict__ out) {
    const int t0 = blockIdx.x * TR;
    const int cnt = 2 * (t0 / ARB) + 2;           // uniform per block
    __shared__ float red[16][16][12];             // 12 KB
    __shared__ float res[TR][12];
    {
        const int r = threadIdx.x >> 4;           // 0..15
        const int s = threadIdx.x & 15;           // 0..15
        float a[12];
#pragma unroll
        for (int d = 0; d < 12; ++d) a[d] = 0.f;
        const size_t S = (size_t)T_SEQ * 12;
        const float* p = part + (size_t)(t0 + r) * 12;
        for (int c = s; c < cnt; c += 16) {
            const float4* pc = (const float4*)(p + (size_t)c * S);
            float4 x0 = pc[0], x1 = pc[1], x2 = pc[2];
            a[0] += x0.x; a[1] += x0.y; a[2]  += x0.z; a[3]  += x0.w;
            a[4] += x1.x; a[5] += x1.y; a[6]  += x1.z; a[7]  += x1.w;
            a[8] += x2.x; a[9] += x2.y; a[10] += x2.z; a[11] += x2.w;
        }
#pragma unroll
        for (int d = 0; d < 12; ++d) red[r][s][d] = a[d];
    }
    __syncthreads();
    if (threadIdx.x < TR * 12) {
        const int r = threadIdx.x / 12, d = threadIdx.x % 12;
        float sum = 0.f;
#pragma unroll
        for (int s = 0; s < 16; ++s) sum += red[r][s][d];
        res[r][d] = (d == 11) ? (1.f / sum) : sum;
    }
    __syncthreads();

    const int e0 = threadIdx.x * 4;
    // direct Wf read: 4 rows x 11 floats = 176B contiguous per thread
    float w[4][11];
    const float* wp = Wf + (size_t)e0 * 11;
#pragma unroll
    for (int ee = 0; ee < 4; ++ee)
#pragma unroll
        for (int i = 0; i < 11; ++i) w[ee][i] = wp[ee * 11 + i];
    const float4 bv = *(const float4*)(bf + e0);

    for (int r = 0; r < TR; ++r) {
        float rr[12];
#pragma unroll
        for (int d = 0; d < 12; ++d) rr[d] = res[r][d];
        float2 a0 = f2(0.f, 0.f), a1 = a0, a2 = a0, a3 = a0;
#pragma unroll
        for (int d = 0; d < 10; d += 2) {
            float2 rv = f2(rr[d], rr[d + 1]);
            a0 = pkfma(rv, f2(w[0][d], w[0][d + 1]), a0);
            a1 = pkfma(rv, f2(w[1][d], w[1][d + 1]), a1);
            a2 = pkfma(rv, f2(w[2][d], w[2][d + 1]), a2);
            a3 = pkfma(rv, f2(w[3][d], w[3][d + 1]), a3);
        }
        const float rl = rr[11];
        float4 ov;
        ov.x = (a0.x + a0.y + rr[10] * w[0][10]) * rl + bv.x;
        ov.y = (a1.x + a1.y + rr[10] * w[1][10]) * rl + bv.y;
        ov.z = (a2.x + a2.y + rr[10] * w[2][10]) * rl + bv.z;
        ov.w = (a3.x + a3.y + rr[10] * w[3][10]) * rl + bv.w;
        *(float4*)(out + (size_t)(t0 + r) * E_DIM + e0) = ov;
    }
}

// ---------------------------------------------------------------------------
extern "C" void kernel_launch(void* const* d_in, const int* in_sizes, int n_in,
                              void* d_out, int out_size, void* d_ws, size_t ws_size,
                              hipStream_t stream) {
    const float* xe = (const float*)d_in[1];
    const float* Wk = (const float*)d_in[2];
    const float* bk = (const float*)d_in[3];
    const float* Wq = (const float*)d_in[4];
    const float* bq = (const float*)d_in[5];
    const float* Wv = (const float*)d_in[6];
    const float* bv = (const float*)d_in[7];
    const float* Wf = (const float*)d_in[8];
    const float* bf = (const float*)d_in[9];
    float* out = (float*)d_out;

    float* qkvF  = (float*)d_ws;                              // [T][QS]
    float* partQ = qkvF + (size_t)T_SEQ * QS;                 // [16][T][QS]
    float* part  = partQ;                                     // overlay: [64][T][12]

    qkv_proj<<<dim3(T_SEQ / QRB, QNEC), 256, 0, stream>>>(xe, Wk, bk, Wq, bq, Wv, bv, partQ);
    reduceQ<<<(T_SEQ * QS / 4) / 256, 256, 0, stream>>>(partQ, qkvF);
    const int nrg = T_SEQ / ARB;                              // 32
    attn<<<nrg * (nrg + 1), 512, 0, stream>>>(qkvF, part);    // 1056 blocks x 8 waves
    pass2<<<T_SEQ / TR, 256, 0, stream>>>(part, Wf, bf, out);
}

// Round 9
// 176.121 us; speedup vs baseline: 1.0005x; 1.0005x over previous
//
#include <hip/hip_runtime.h>

#define T_SEQ 8192
#define E_DIM 1024
#define QS 36              // padded qkv row: [k 0..10][pad][q 12..22][pad][v 24..34][pad]
#define QNEC 16            // E-chunk grid dim (x2 32-col sub-chunks in-kernel)
#define QKC 32             // cols per qkv sub-chunk
#define QX4 8              // QKC/4 float4-cols
#define QXST 9             // padded f4 stride: 36 words = 4 mod 32 -> clean b128 rotation
#define QRB 128            // qkv rows per block (2/lane)
#define AJW 16             // attn j per wave
#define ABJ 128            // attn j per block (8 waves)
#define ARB 256            // attn rows per row-group (4/lane)
#define KVW 24             // LDS kv row: [k0..10,pad][v0..10,pad]
#define TR 16              // pass2 rows per block

__device__ __forceinline__ float2 pkfma(float2 a, float2 b, float2 c) {
    return make_float2(fmaf(a.x, b.x, c.x), fmaf(a.y, b.y, c.y));
}
__device__ __forceinline__ float2 f2(float x, float y) { return make_float2(x, y); }

// pack a 6-f2 output row into 3 f4 at stride 64 f4 (slot-major LDS layout)
__device__ __forceinline__ void pack3s(const float2 o[6], float4* dst) {
    float4 t;
    t.x = o[0].x; t.y = o[0].y; t.z = o[1].x; t.w = o[1].y; dst[0]   = t;
    t.x = o[2].x; t.y = o[2].y; t.z = o[3].x; t.w = o[3].y; dst[64]  = t;
    t.x = o[4].x; t.y = o[4].y; t.z = o[5].x; t.w = o[5].y; dst[128] = t;
}
// pack for global store (contiguous 3 f4)
__device__ __forceinline__ void pack3(const float2 o[6], float4* dst) {
    float4 t;
    t.x = o[0].x; t.y = o[0].y; t.z = o[1].x; t.w = o[1].y; dst[0] = t;
    t.x = o[2].x; t.y = o[2].y; t.z = o[3].x; t.w = o[3].y; dst[1] = t;
    t.x = o[4].x; t.y = o[4].y; t.z = o[5].x; t.w = o[5].y; dst[2] = t;
}

// ws floats: qkvF[T][QS] 1.18MB | region R: partQ[16][T][QS] 18.9MB overlaid
//   by part[64][T][12] 25.2MB (partQ dead after reduceQ; stream-ordered).
//   ~26.4MB total (proven-safe). NO atomics (R4: device fp atomicAdd = 32B
//   HBM write-through each, 10x cost). Combine LDS layout is SLOT-MAJOR
//   (lane-contiguous 16B stride): R8's lane-major 192B stride = 48-word lane
//   stride = 2-bank pattern -> 3.19M bank-conflict cycles measured.

// ---------------------------------------------------------------------------
// K1: qkv projection, 2 rows/lane. Block 256 thr = 128 rows x 4 col-groups;
// 2 sub-chunks of 32 cols in-kernel. Per c4-iter: 2 per-lane b128 x-reads +
// 9 broadcast b128 w-reads -> 72 v_fma. LDS 23KB; grid dim3(64,16) = 1024 =
// 4.0 blocks/CU uniform (16 waves/CU). Epilogue transposes through LDS.
// ---------------------------------------------------------------------------
__global__ __launch_bounds__(256) void qkv_proj(
    const float* __restrict__ xe,
    const float* __restrict__ Wk, const float* __restrict__ bk,
    const float* __restrict__ Wq, const float* __restrict__ bq,
    const float* __restrict__ Wv, const float* __restrict__ bv,
    float* __restrict__ partQ) {
    const int row0 = blockIdx.x * QRB;
    const int ec = blockIdx.y;
    const int lane = threadIdx.x & 63;
    const int wg = threadIdx.x >> 6;

    __shared__ float4 xT[QRB * QXST];     // 18.4 KB
    __shared__ float4 wT[36 * QX4];       // 4.6 KB

    float2 acc[2][9];
#pragma unroll
    for (int u = 0; u < 2; ++u)
#pragma unroll
        for (int k = 0; k < 9; ++k) acc[u][k] = f2(0.f, 0.f);

    for (int cc = 0; cc < 2; ++cc) {
        const int cb = ec * 64 + cc * QKC;
        if (cc) __syncthreads();          // WAR on xT/wT

        // stage xe tile: 1024 f4, 4/thread, 8 threads per 128B row segment
#pragma unroll
        for (int t = 0; t < 4; ++t) {
            int idx = threadIdx.x + t * 256;
            int r = idx >> 3, c4 = idx & 7;
            xT[r * QXST + c4] =
                *(const float4*)(xe + (size_t)(row0 + r) * E_DIM + cb + c4 * 4);
        }
        // stage W tile: 36 rows x 8 f4 (rows 33..35 zero)
        for (int idx = threadIdx.x; idx < 36 * QX4; idx += 256) {
            int r = idx >> 3, c4 = idx & 7;
            float4 v = make_float4(0.f, 0.f, 0.f, 0.f);
            if (r < 33) {
                const float* base = (r < 11) ? (Wk + (size_t)r * E_DIM)
                                  : (r < 22) ? (Wq + (size_t)(r - 11) * E_DIM)
                                             : (Wv + (size_t)(r - 22) * E_DIM);
                v = *(const float4*)(base + cb + c4 * 4);
            }
            wT[idx] = v;
        }
        __syncthreads();

        const float4* xr = xT + lane * QXST;
        const float4* wr = wT + wg * 9 * QX4;
#pragma unroll
        for (int c4 = 0; c4 < QX4; ++c4) {
            float4 xv0 = xr[c4];
            float4 xv1 = xr[64 * QXST + c4];
#pragma unroll
            for (int k = 0; k < 9; ++k) {
                float4 wv = wr[k * QX4 + c4];          // broadcast
                float2 wlo = f2(wv.x, wv.y), whi = f2(wv.z, wv.w);
                acc[0][k] = pkfma(f2(xv0.x, xv0.y), wlo, acc[0][k]);
                acc[0][k] = pkfma(f2(xv0.z, xv0.w), whi, acc[0][k]);
                acc[1][k] = pkfma(f2(xv1.x, xv1.y), wlo, acc[1][k]);
                acc[1][k] = pkfma(f2(xv1.z, xv1.w), whi, acc[1][k]);
            }
        }
    }

    // transpose through LDS (res overlays xT exactly: 128*36 floats = 18.4KB)
    __syncthreads();
    float* res = (float*)xT;
#pragma unroll
    for (int k = 0; k < 9; ++k) {
        int o = wg * 9 + k;
        bool live = (o < 33);
        int c = (o < 11) ? o : (o < 22) ? o + 1 : (o < 33) ? o + 2
              : (o == 33) ? 11 : (o == 34) ? 23 : 35;
        float b = 0.f;
        if (ec == 0 && live)
            b = (o < 11) ? bk[o] : (o < 22) ? bq[o - 11] : bv[o - 22];
        res[lane * 36 + c]        = live ? (acc[0][k].x + acc[0][k].y + b) : 0.f;
        res[(lane + 64) * 36 + c] = live ? (acc[1][k].x + acc[1][k].y + b) : 0.f;
    }
    __syncthreads();

    // coalesced f4 write: 128 rows x 9 f4 = 1152 contiguous f4
    float4* dst = (float4*)(partQ + ((size_t)ec * T_SEQ + row0) * QS);
    for (int idx = threadIdx.x; idx < QRB * 9; idx += 256) {
        int r = idx / 9, f = idx % 9;
        dst[idx] = *(const float4*)(res + r * 36 + f * 4);
    }
}

// ---------------------------------------------------------------------------
// K2: reduce QNEC qkv partial chunks into dense qkvF. 18.9MB read, 1.2MB write.
// ---------------------------------------------------------------------------
__global__ __launch_bounds__(256) void reduceQ(const float* __restrict__ partQ,
                                               float* __restrict__ qkvF) {
    const size_t idx = (size_t)blockIdx.x * 256 + threadIdx.x;
    const float4* p = (const float4*)partQ;
    const size_t cs = (size_t)T_SEQ * (QS / 4);
    float4 s = make_float4(0.f, 0.f, 0.f, 0.f);
#pragma unroll
    for (int c = 0; c < QNEC; ++c) {
        float4 a = p[idx + (size_t)c * cs];
        s.x += a.x; s.y += a.y; s.z += a.z; s.w += a.w;
    }
    ((float4*)qkvF)[idx] = s;
}

// ---------------------------------------------------------------------------
// K3: causal attention, 8-WAVE blocks (512 thr), 4 rows/lane, 16 j/wave.
// Block b -> (rb, c): prefix(rb) = rb(rb+1), c in [0, 2rb+2) — covers 128 j.
// Wave w: j0 = c*128 + w*16. 1056 blocks x 8 waves; LDS 48KB -> 3 blocks/CU
// = 24 waves/CU = 6/SIMD. 3-round SLOT-MAJOR LDS tree (red[buf][slot][lane],
// lane stride 16B = conflict-free b128; R8's lane-major was 32-way) folds 8
// waves; wave 0 writes ONE slot c of part[64][T][12]. NO atomics.
// ---------------------------------------------------------------------------
__global__ __launch_bounds__(512) void attn(const float* __restrict__ qkvF,
                                            float* __restrict__ part) {
    const int b = blockIdx.x;
    int rb = 0;
    while ((rb + 1) * (rb + 2) <= b) ++rb;        // prefix(rb) = rb(rb+1)
    const int c = b - rb * (rb + 1);              // c in [0, 2rb+2)
    const int lane = threadIdx.x & 63;
    const int wid = threadIdx.x >> 6;
    const int r0 = rb * ARB + lane * 4;
    const int j0 = c * ABJ + wid * AJW;

    __shared__ float sh[12288];                   // 48KB: kv[8][384] | red 4x12KB
    float* kv = sh + wid * (AJW * KVW);           // wave-private 1.5KB

    // q for 4 rows, packed as 6 f2 each (pair 5 = (q10, 0))
    float2 q[4][6], o[4][6];
#pragma unroll
    for (int i = 0; i < 4; ++i) {
        const float* qp = qkvF + (size_t)(r0 + i) * QS + 12;
#pragma unroll
        for (int d = 0; d < 5; ++d) q[i][d] = f2(qp[2 * d], qp[2 * d + 1]);
        q[i][5] = f2(qp[10], 0.f);
#pragma unroll
        for (int d = 0; d < 6; ++d) o[i][d] = f2(0.f, 0.f);
    }

    // stage 16 rows x 6 f4 = 96 f4 (wave-private; within-wave lgkmcnt ordering)
#pragma unroll
    for (int t = 0; t < 2; ++t) {
        int idx = lane + t * 64;
        if (idx < AJW * 6) {
            int row = idx / 6, f = idx % 6;
            int srcOff = f * 4 + (f >= 3 ? 12 : 0);
            float4 v = *(const float4*)(qkvF + (size_t)(j0 + row) * QS + srcOff);
            *(float4*)(kv + row * KVW + f * 4) = v;
        }
    }

    for (int jj = 0; jj < AJW; ++jj) {
        const float* kp = kv + jj * KVW;
        const float4 kA = *(const float4*)(kp);
        const float4 kB = *(const float4*)(kp + 4);
        const float4 kC = *(const float4*)(kp + 8);   // .w = 0 (pad)
        const float4 vA = *(const float4*)(kp + 12);
        const float4 vB = *(const float4*)(kp + 16);
        const float4 vC = *(const float4*)(kp + 20);  // .w = 0 (pad)
        const float2 k01 = f2(kA.x, kA.y), k23 = f2(kA.z, kA.w);
        const float2 k45 = f2(kB.x, kB.y), k67 = f2(kB.z, kB.w);
        const float2 k89 = f2(kC.x, kC.y), kXp = f2(kC.z, kC.w);
        const int j = j0 + jj;

#pragma unroll
        for (int i = 0; i < 4; ++i) {
            float2 s = pkfma(q[i][0], k01, pkfma(q[i][1], k23, pkfma(q[i][2], k45,
                       pkfma(q[i][3], k67, pkfma(q[i][4], k89,
                       pkfma(q[i][5], kXp, f2(0.f, 0.f)))))));
            float pe = __expf(s.x + s.y);
            pe = (j <= r0 + i) ? pe : 0.f;
            float2 p2 = f2(pe, pe);
            o[i][0] = pkfma(p2, f2(vA.x, vA.y), o[i][0]);
            o[i][1] = pkfma(p2, f2(vA.z, vA.w), o[i][1]);
            o[i][2] = pkfma(p2, f2(vB.x, vB.y), o[i][2]);
            o[i][3] = pkfma(p2, f2(vB.z, vB.w), o[i][3]);
            o[i][4] = pkfma(p2, f2(vC.x, vC.y), o[i][4]);
            o[i][5] = pkfma(p2, f2(vC.z, 1.f),  o[i][5]);   // o10, l
        }
    }

    // 3-round tree combine, slot-major: red[buf][slot(12)][lane(64)] f4
    float4* red = (float4*)sh;                    // 4 bufs x 768 f4 (12KB)
    __syncthreads();
    if (wid >= 4) {
        float4* dst = red + (size_t)(wid - 4) * 768 + lane;
#pragma unroll
        for (int i = 0; i < 4; ++i) pack3s(o[i], dst + (i * 3) * 64);
    }
    __syncthreads();
    if (wid < 4) {
        const float4* src = red + (size_t)wid * 768 + lane;
#pragma unroll
        for (int i = 0; i < 4; ++i) {
            float4 s0 = src[(i * 3 + 0) * 64], s1 = src[(i * 3 + 1) * 64],
                   s2 = src[(i * 3 + 2) * 64];
            o[i][0].x += s0.x; o[i][0].y += s0.y; o[i][1].x += s0.z; o[i][1].y += s0.w;
            o[i][2].x += s1.x; o[i][2].y += s1.y; o[i][3].x += s1.z; o[i][3].y += s1.w;
            o[i][4].x += s2.x; o[i][4].y += s2.y; o[i][5].x += s2.z; o[i][5].y += s2.w;
        }
    }
    __syncthreads();
    if (wid == 2 || wid == 3) {
        float4* dst = red + (size_t)(wid - 2) * 768 + lane;
#pragma unroll
        for (int i = 0; i < 4; ++i) pack3s(o[i], dst + (i * 3) * 64);
    }
    __syncthreads();
    if (wid < 2) {
        const float4* src = red + (size_t)wid * 768 + lane;
#pragma unroll
        for (int i = 0; i < 4; ++i) {
            float4 s0 = src[(i * 3 + 0) * 64], s1 = src[(i * 3 + 1) * 64],
                   s2 = src[(i * 3 + 2) * 64];
            o[i][0].x += s0.x; o[i][0].y += s0.y; o[i][1].x += s0.z; o[i][1].y += s0.w;
            o[i][2].x += s1.x; o[i][2].y += s1.y; o[i][3].x += s1.z; o[i][3].y += s1.w;
            o[i][4].x += s2.x; o[i][4].y += s2.y; o[i][5].x += s2.z; o[i][5].y += s2.w;
        }
    }
    __syncthreads();
    if (wid == 1) {
        float4* dst = red + lane;
#pragma unroll
        for (int i = 0; i < 4; ++i) pack3s(o[i], dst + (i * 3) * 64);
    }
    __syncthreads();
    if (wid == 0) {
        const float4* src = red + lane;
#pragma unroll
        for (int i = 0; i < 4; ++i) {
            float4 s0 = src[(i * 3 + 0) * 64], s1 = src[(i * 3 + 1) * 64],
                   s2 = src[(i * 3 + 2) * 64];
            o[i][0].x += s0.x; o[i][0].y += s0.y; o[i][1].x += s0.z; o[i][1].y += s0.w;
            o[i][2].x += s1.x; o[i][2].y += s1.y; o[i][3].x += s1.z; o[i][3].y += s1.w;
            o[i][4].x += s2.x; o[i][4].y += s2.y; o[i][5].x += s2.z; o[i][5].y += s2.w;
        }
        float* d0 = part + ((size_t)c * T_SEQ + r0) * 12;
#pragma unroll
        for (int i = 0; i < 4; ++i) pack3(o[i], (float4*)(d0 + i * 12));
    }
}

// ---------------------------------------------------------------------------
// K4: fused partial-reduce + normalize + output GEMM + bias. 16-way parallel
// slot reduction: 256 thr = 16 rows x 16 slot-groups, <=4 independent rounds,
// LDS tree-combine. Wf read directly (4 contiguous 11-float rows/thread,
// L3-resident). cnt for row t: 2*(t/256)+2 <= 64, uniform per block.
// ---------------------------------------------------------------------------
__global__ __launch_bounds__(256) void pass2(const float* __restrict__ part,
                                             const float* __restrict__ Wf,
                                             const float* __restrict__ bf,
                                             float* __restrict__ out) {
    const int t0 = blockIdx.x * TR;
    const int cnt = 2 * (t0 / ARB) + 2;           // uniform per block
    __shared__ float red[16][16][12];             // 12 KB
    __shared__ float res[TR][12];
    {
        const int r = threadIdx.x >> 4;           // 0..15
        const int s = threadIdx.x & 15;           // 0..15
        float a[12];
#pragma unroll
        for (int d = 0; d < 12; ++d) a[d] = 0.f;
        const size_t S = (size_t)T_SEQ * 12;
        const float* p = part + (size_t)(t0 + r) * 12;
        for (int c = s; c < cnt; c += 16) {
            const float4* pc = (const float4*)(p + (size_t)c * S);
            float4 x0 = pc[0], x1 = pc[1], x2 = pc[2];
            a[0] += x0.x; a[1] += x0.y; a[2]  += x0.z; a[3]  += x0.w;
            a[4] += x1.x; a[5] += x1.y; a[6]  += x1.z; a[7]  += x1.w;
            a[8] += x2.x; a[9] += x2.y; a[10] += x2.z; a[11] += x2.w;
        }
#pragma unroll
        for (int d = 0; d < 12; ++d) red[r][s][d] = a[d];
    }
    __syncthreads();
    if (threadIdx.x < TR * 12) {
        const int r = threadIdx.x / 12, d = threadIdx.x % 12;
        float sum = 0.f;
#pragma unroll
        for (int s = 0; s < 16; ++s) sum += red[r][s][d];
        res[r][d] = (d == 11) ? (1.f / sum) : sum;
    }
    __syncthreads();

    const int e0 = threadIdx.x * 4;
    // direct Wf read: 4 rows x 11 floats = 176B contiguous per thread
    float w[4][11];
    const float* wp = Wf + (size_t)e0 * 11;
#pragma unroll
    for (int ee = 0; ee < 4; ++ee)
#pragma unroll
        for (int i = 0; i < 11; ++i) w[ee][i] = wp[ee * 11 + i];
    const float4 bv = *(const float4*)(bf + e0);

    for (int r = 0; r < TR; ++r) {
        float rr[12];
#pragma unroll
        for (int d = 0; d < 12; ++d) rr[d] = res[r][d];
        float2 a0 = f2(0.f, 0.f), a1 = a0, a2 = a0, a3 = a0;
#pragma unroll
        for (int d = 0; d < 10; d += 2) {
            float2 rv = f2(rr[d], rr[d + 1]);
            a0 = pkfma(rv, f2(w[0][d], w[0][d + 1]), a0);
            a1 = pkfma(rv, f2(w[1][d], w[1][d + 1]), a1);
            a2 = pkfma(rv, f2(w[2][d], w[2][d + 1]), a2);
            a3 = pkfma(rv, f2(w[3][d], w[3][d + 1]), a3);
        }
        const float rl = rr[11];
        float4 ov;
        ov.x = (a0.x + a0.y + rr[10] * w[0][10]) * rl + bv.x;
        ov.y = (a1.x + a1.y + rr[10] * w[1][10]) * rl + bv.y;
        ov.z = (a2.x + a2.y + rr[10] * w[2][10]) * rl + bv.z;
        ov.w = (a3.x + a3.y + rr[10] * w[3][10]) * rl + bv.w;
        *(float4*)(out + (size_t)(t0 + r) * E_DIM + e0) = ov;
    }
}

// ---------------------------------------------------------------------------
extern "C" void kernel_launch(void* const* d_in, const int* in_sizes, int n_in,
                              void* d_out, int out_size, void* d_ws, size_t ws_size,
                              hipStream_t stream) {
    const float* xe = (const float*)d_in[1];
    const float* Wk = (const float*)d_in[2];
    const float* bk = (const float*)d_in[3];
    const float* Wq = (const float*)d_in[4];
    const float* bq = (const float*)d_in[5];
    const float* Wv = (const float*)d_in[6];
    const float* bv = (const float*)d_in[7];
    const float* Wf = (const float*)d_in[8];
    const float* bf = (const float*)d_in[9];
    float* out = (float*)d_out;

    float* qkvF  = (float*)d_ws;                              // [T][QS]
    float* partQ = qkvF + (size_t)T_SEQ * QS;                 // [16][T][QS]
    float* part  = partQ;                                     // overlay: [64][T][12]

    qkv_proj<<<dim3(T_SEQ / QRB, QNEC), 256, 0, stream>>>(xe, Wk, bk, Wq, bq, Wv, bv, partQ);
    reduceQ<<<(T_SEQ * QS / 4) / 256, 256, 0, stream>>>(partQ, qkvF);
    const int nrg = T_SEQ / ARB;                              // 32
    attn<<<nrg * (nrg + 1), 512, 0, stream>>>(qkvF, part);    // 1056 blocks x 8 waves
    pass2<<<T_SEQ / TR, 256, 0, stream>>>(part, Wf, bf, out);
}

// Round 11
// 163.832 us; speedup vs baseline: 1.0755x; 1.0750x over previous
//
#include <hip/hip_runtime.h>

#define T_SEQ 8192
#define E_DIM 1024
#define QS 36              // padded qkv row: [k 0..10][pad][q 12..22][pad][v 24..34][pad]
#define QNEC 8             // E-chunks in qkv projection (x2 64-col sub-chunks in-kernel)
#define QKC 64             // cols per qkv sub-chunk
#define QX4 16             // QKC/4 float4-cols
#define QXST 17            // f4 stride: 68 words = 4 mod 32 -> clean 4-word bank rotation
#define QRB 64             // qkv rows per block (1/lane)
#define AJW 16             // attn j per wave
#define ABJ 64             // attn j per block (4 waves)
#define ARB 256            // attn rows per row-group (4/lane)
#define KVW 24             // LDS kv row: [k0..10,pad][v0..10,pad]
#define TR 16              // pass2 rows per block

__device__ __forceinline__ float2 pkfma(float2 a, float2 b, float2 c) {
    return make_float2(fmaf(a.x, b.x, c.x), fmaf(a.y, b.y, c.y));
}
__device__ __forceinline__ float2 f2(float x, float y) { return make_float2(x, y); }

// pack a 6-f2 output row into 3 f4 at stride 64 f4 (slot-major LDS layout:
// lane-contiguous 16B stride = conflict-free b128; R8's lane-major 192B
// stride measured 3.19M conflict cycles)
__device__ __forceinline__ void pack3s(const float2 o[6], float4* dst) {
    float4 t;
    t.x = o[0].x; t.y = o[0].y; t.z = o[1].x; t.w = o[1].y; dst[0]   = t;
    t.x = o[2].x; t.y = o[2].y; t.z = o[3].x; t.w = o[3].y; dst[64]  = t;
    t.x = o[4].x; t.y = o[4].y; t.z = o[5].x; t.w = o[5].y; dst[128] = t;
}
__device__ __forceinline__ void pack3(const float2 o[6], float4* dst) {
    float4 t;
    t.x = o[0].x; t.y = o[0].y; t.z = o[1].x; t.w = o[1].y; dst[0] = t;
    t.x = o[2].x; t.y = o[2].y; t.z = o[3].x; t.w = o[3].y; dst[1] = t;
    t.x = o[4].x; t.y = o[4].y; t.z = o[5].x; t.w = o[5].y; dst[2] = t;
}
__device__ __forceinline__ void add3s(float2 o[6], const float4* src) {
    float4 s0 = src[0], s1 = src[64], s2 = src[128];
    o[0].x += s0.x; o[0].y += s0.y; o[1].x += s0.z; o[1].y += s0.w;
    o[2].x += s1.x; o[2].y += s1.y; o[3].x += s1.z; o[3].y += s1.w;
    o[4].x += s2.x; o[4].y += s2.y; o[5].x += s2.z; o[5].y += s2.w;
}

// ws floats: qkvF[T][QS] 1.18MB | region R: partQ[8][T][QS] 9.4MB overlaid by
//   part[128][T][12] 50.3MB (partQ dead after reduceQ; stream-ordered).
//   ~51.5MB total; ws = 256MB. NO atomics (R4: device fp atomicAdd = 32B HBM
//   write-through, 10x cost).

// ---------------------------------------------------------------------------
// K1: qkv projection (R7-proven config; R8's 2-row variant coincided with +7us
// and is reverted). Block 256 thr = 64 rows x 4 col-groups, 1 row/lane; 2
// sub-chunks of 64 cols in-kernel. LDS 26.6KB; grid dim3(128,8) = 1024 = 4.0
// blocks/CU uniform (16 waves/CU). Epilogue transposes through LDS.
// ---------------------------------------------------------------------------
__global__ __launch_bounds__(256) void qkv_proj(
    const float* __restrict__ xe,
    const float* __restrict__ Wk, const float* __restrict__ bk,
    const float* __restrict__ Wq, const float* __restrict__ bq,
    const float* __restrict__ Wv, const float* __restrict__ bv,
    float* __restrict__ partQ) {
    const int row0 = blockIdx.x * QRB;
    const int ec = blockIdx.y;
    const int lane = threadIdx.x & 63;
    const int wg = threadIdx.x >> 6;

    __shared__ float4 xT[QRB * QXST];     // 17.4 KB
    __shared__ float4 wT[36 * QX4];       // 9.2 KB

    float2 acc[9];
#pragma unroll
    for (int k = 0; k < 9; ++k) acc[k] = f2(0.f, 0.f);

    for (int cc = 0; cc < 2; ++cc) {
        const int cb = ec * 128 + cc * QKC;
        if (cc) __syncthreads();          // WAR on xT/wT

        // stage xe tile: 1024 f4, 4/thread, 16 threads per 256B row
#pragma unroll
        for (int t = 0; t < 4; ++t) {
            int idx = threadIdx.x + t * 256;
            int r = idx >> 4, c4 = idx & 15;
            xT[r * QXST + c4] =
                *(const float4*)(xe + (size_t)(row0 + r) * E_DIM + cb + c4 * 4);
        }
        // stage W tile: 36 rows x 16 f4 (rows 33..35 zero)
        for (int idx = threadIdx.x; idx < 36 * QX4; idx += 256) {
            int r = idx >> 4, c4 = idx & 15;
            float4 v = make_float4(0.f, 0.f, 0.f, 0.f);
            if (r < 33) {
                const float* base = (r < 11) ? (Wk + (size_t)r * E_DIM)
                                  : (r < 22) ? (Wq + (size_t)(r - 11) * E_DIM)
                                             : (Wv + (size_t)(r - 22) * E_DIM);
                v = *(const float4*)(base + cb + c4 * 4);
            }
            wT[idx] = v;
        }
        __syncthreads();

        const float4* xr = xT + lane * QXST;
        const float4* wr = wT + wg * 9 * QX4;
#pragma unroll 4
        for (int c4 = 0; c4 < QX4; ++c4) {
            float4 xv = xr[c4];
#pragma unroll
            for (int k = 0; k < 9; ++k) {
                float4 wv = wr[k * QX4 + c4];          // broadcast
                acc[k] = pkfma(f2(xv.x, xv.y), f2(wv.x, wv.y), acc[k]);
                acc[k] = pkfma(f2(xv.z, xv.w), f2(wv.z, wv.w), acc[k]);
            }
        }
    }

    // transpose through LDS (overlay on xT, dead after compute)
    __syncthreads();
    float* res = (float*)xT;                      // [64][36], 9.2KB
#pragma unroll
    for (int k = 0; k < 9; ++k) {
        int o = wg * 9 + k;
        bool live = (o < 33);
        int c = (o < 11) ? o : (o < 22) ? o + 1 : (o < 33) ? o + 2
              : (o == 33) ? 11 : (o == 34) ? 23 : 35;
        float b = 0.f;
        if (ec == 0 && live)
            b = (o < 11) ? bk[o] : (o < 22) ? bq[o - 11] : bv[o - 22];
        res[lane * 36 + c] = live ? (acc[k].x + acc[k].y + b) : 0.f;
    }
    __syncthreads();

    // coalesced f4 write: 64 rows x 9 f4 = 576 contiguous f4
    float4* dst = (float4*)(partQ + ((size_t)ec * T_SEQ + row0) * QS);
    for (int idx = threadIdx.x; idx < QRB * 9; idx += 256) {
        int r = idx / 9, f = idx % 9;
        dst[idx] = *(const float4*)(res + r * 36 + f * 4);
    }
}

// ---------------------------------------------------------------------------
// K2: reduce QNEC qkv partial chunks into dense qkvF. 9.4MB read, 1.2MB write.
// ---------------------------------------------------------------------------
__global__ __launch_bounds__(256) void reduceQ(const float* __restrict__ partQ,
                                               float* __restrict__ qkvF) {
    const size_t idx = (size_t)blockIdx.x * 256 + threadIdx.x;
    const float4* p = (const float4*)partQ;
    const size_t cs = (size_t)T_SEQ * (QS / 4);
    float4 s = make_float4(0.f, 0.f, 0.f, 0.f);
#pragma unroll
    for (int c = 0; c < QNEC; ++c) {
        float4 a = p[idx + (size_t)c * cs];
        s.x += a.x; s.y += a.y; s.z += a.z; s.w += a.w;
    }
    ((float4*)qkvF)[idx] = s;
}

// ---------------------------------------------------------------------------
// K3: causal attention, THIN 4-wave blocks (256 thr), 4 rows/lane, 16 j/wave,
// 64 j/block. Block b -> (rb, c): prefix(rb) = 2rb(rb+1), c in [0, 4rb+4).
// Grid 2112 blocks; LDS 12KB -> 8 blocks/CU (thread-limited) = 32 waves/CU,
// device capacity 2048 blocks -> ~single phase (R8/R9's 1056x512thr/48KB shape
// ran 1.4 phases -> measured 27.9% occupancy, the real attn limiter). After
// the jj loop a 6-barrier single-buffer slot-major tree (12KB, overlays dead
// kv) folds 4 waves; wave 0 writes ONE slot c of part[128][T][12]. NO atomics.
// ---------------------------------------------------------------------------
__global__ __launch_bounds__(256) void attn(const float* __restrict__ qkvF,
                                            float* __restrict__ part) {
    const int b = blockIdx.x;
    int rb = 0;
    while (2 * (rb + 1) * (rb + 2) <= b) ++rb;    // prefix(rb) = 2rb(rb+1)
    const int c = b - 2 * rb * (rb + 1);          // c in [0, 4rb+4)
    const int lane = threadIdx.x & 63;
    const int wid = threadIdx.x >> 6;
    const int r0 = rb * ARB + lane * 4;
    const int j0 = c * ABJ + wid * AJW;

    __shared__ float sh[3072];                    // 12KB: kv[4][384] | tree buf
    float* kv = sh + wid * (AJW * KVW);           // wave-private 1.5KB

    // q for 4 rows, packed as 6 f2 each (pair 5 = (q10, 0))
    float2 q[4][6], o[4][6];
#pragma unroll
    for (int i = 0; i < 4; ++i) {
        const float* qp = qkvF + (size_t)(r0 + i) * QS + 12;
#pragma unroll
        for (int d = 0; d < 5; ++d) q[i][d] = f2(qp[2 * d], qp[2 * d + 1]);
        q[i][5] = f2(qp[10], 0.f);
#pragma unroll
        for (int d = 0; d < 6; ++d) o[i][d] = f2(0.f, 0.f);
    }

    // stage 16 rows x 6 f4 = 96 f4 (wave-private; within-wave lgkmcnt ordering)
#pragma unroll
    for (int t = 0; t < 2; ++t) {
        int idx = lane + t * 64;
        if (idx < AJW * 6) {
            int row = idx / 6, f = idx % 6;
            int srcOff = f * 4 + (f >= 3 ? 12 : 0);
            float4 v = *(const float4*)(qkvF + (size_t)(j0 + row) * QS + srcOff);
            *(float4*)(kv + row * KVW + f * 4) = v;
        }
    }

    for (int jj = 0; jj < AJW; ++jj) {
        const float* kp = kv + jj * KVW;
        const float4 kA = *(const float4*)(kp);
        const float4 kB = *(const float4*)(kp + 4);
        const float4 kC = *(const float4*)(kp + 8);   // .w = 0 (pad)
        const float4 vA = *(const float4*)(kp + 12);
        const float4 vB = *(const float4*)(kp + 16);
        const float4 vC = *(const float4*)(kp + 20);  // .w = 0 (pad)
        const float2 k01 = f2(kA.x, kA.y), k23 = f2(kA.z, kA.w);
        const float2 k45 = f2(kB.x, kB.y), k67 = f2(kB.z, kB.w);
        const float2 k89 = f2(kC.x, kC.y), kXp = f2(kC.z, kC.w);
        const int j = j0 + jj;

#pragma unroll
        for (int i = 0; i < 4; ++i) {
            float2 s = pkfma(q[i][0], k01, pkfma(q[i][1], k23, pkfma(q[i][2], k45,
                       pkfma(q[i][3], k67, pkfma(q[i][4], k89,
                       pkfma(q[i][5], kXp, f2(0.f, 0.f)))))));
            float pe = __expf(s.x + s.y);
            pe = (j <= r0 + i) ? pe : 0.f;
            float2 p2 = f2(pe, pe);
            o[i][0] = pkfma(p2, f2(vA.x, vA.y), o[i][0]);
            o[i][1] = pkfma(p2, f2(vA.z, vA.w), o[i][1]);
            o[i][2] = pkfma(p2, f2(vB.x, vB.y), o[i][2]);
            o[i][3] = pkfma(p2, f2(vB.z, vB.w), o[i][3]);
            o[i][4] = pkfma(p2, f2(vC.x, vC.y), o[i][4]);
            o[i][5] = pkfma(p2, f2(vC.z, 1.f),  o[i][5]);   // o10, l
        }
    }

    // 6-barrier sequential single-buffer tree, slot-major buf[slot(12)][lane]
    float4* buf = (float4*)sh;                    // 768 f4 = 12KB (kv dead)
    __syncthreads();
    if (wid == 1) {
#pragma unroll
        for (int i = 0; i < 4; ++i) pack3s(o[i], buf + (i * 3) * 64 + lane);
    }
    __syncthreads();
    if (wid == 0) {
#pragma unroll
        for (int i = 0; i < 4; ++i) add3s(o[i], buf + (i * 3) * 64 + lane);
    }
    __syncthreads();
    if (wid == 3) {
#pragma unroll
        for (int i = 0; i < 4; ++i) pack3s(o[i], buf + (i * 3) * 64 + lane);
    }
    __syncthreads();
    if (wid == 2) {
#pragma unroll
        for (int i = 0; i < 4; ++i) add3s(o[i], buf + (i * 3) * 64 + lane);
    }
    __syncthreads();
    if (wid == 2) {
#pragma unroll
        for (int i = 0; i < 4; ++i) pack3s(o[i], buf + (i * 3) * 64 + lane);
    }
    __syncthreads();
    if (wid == 0) {
#pragma unroll
        for (int i = 0; i < 4; ++i) add3s(o[i], buf + (i * 3) * 64 + lane);
        float* d0 = part + ((size_t)c * T_SEQ + r0) * 12;
#pragma unroll
        for (int i = 0; i < 4; ++i) pack3(o[i], (float4*)(d0 + i * 12));
    }
}

// ---------------------------------------------------------------------------
// K4: fused partial-reduce + normalize + output GEMM + bias. 16-way parallel
// slot reduction: 256 thr = 16 rows x 16 slot-groups, <=8 independent rounds,
// LDS tree-combine. Wf read directly (4 contiguous 11-float rows/thread,
// L3-resident). cnt for row t: 4*(t/256)+4 <= 128, uniform per block.
// ---------------------------------------------------------------------------
__global__ __launch_bounds__(256) void pass2(const float* __restrict__ part,
                                             const float* __restrict__ Wf,
                                             const float* __restrict__ bf,
                                             float* __restrict__ out) {
    const int t0 = blockIdx.x * TR;
    const int cnt = 4 * (t0 / ARB) + 4;           // uniform per block
    __shared__ float red[16][16][12];             // 12 KB
    __shared__ float res[TR][12];
    {
        const int r = threadIdx.x >> 4;           // 0..15
        const int s = threadIdx.x & 15;           // 0..15
        float a[12];
#pragma unroll
        for (int d = 0; d < 12; ++d) a[d] = 0.f;
        const size_t S = (size_t)T_SEQ * 12;
        const float* p = part + (size_t)(t0 + r) * 12;
        for (int c = s; c < cnt; c += 16) {
            const float4* pc = (const float4*)(p + (size_t)c * S);
            float4 x0 = pc[0], x1 = pc[1], x2 = pc[2];
            a[0] += x0.x; a[1] += x0.y; a[2]  += x0.z; a[3]  += x0.w;
            a[4] += x1.x; a[5] += x1.y; a[6]  += x1.z; a[7]  += x1.w;
            a[8] += x2.x; a[9] += x2.y; a[10] += x2.z; a[11] += x2.w;
        }
#pragma unroll
        for (int d = 0; d < 12; ++d) red[r][s][d] = a[d];
    }
    __syncthreads();
    if (threadIdx.x < TR * 12) {
        const int r = threadIdx.x / 12, d = threadIdx.x % 12;
        float sum = 0.f;
#pragma unroll
        for (int s = 0; s < 16; ++s) sum += red[r][s][d];
        res[r][d] = (d == 11) ? (1.f / sum) : sum;
    }
    __syncthreads();

    const int e0 = threadIdx.x * 4;
    // direct Wf read: 4 rows x 11 floats = 176B contiguous per thread
    float w[4][11];
    const float* wp = Wf + (size_t)e0 * 11;
#pragma unroll
    for (int ee = 0; ee < 4; ++ee)
#pragma unroll
        for (int i = 0; i < 11; ++i) w[ee][i] = wp[ee * 11 + i];
    const float4 bv = *(const float4*)(bf + e0);

    for (int r = 0; r < TR; ++r) {
        float rr[12];
#pragma unroll
        for (int d = 0; d < 12; ++d) rr[d] = res[r][d];
        float2 a0 = f2(0.f, 0.f), a1 = a0, a2 = a0, a3 = a0;
#pragma unroll
        for (int d = 0; d < 10; d += 2) {
            float2 rv = f2(rr[d], rr[d + 1]);
            a0 = pkfma(rv, f2(w[0][d], w[0][d + 1]), a0);
            a1 = pkfma(rv, f2(w[1][d], w[1][d + 1]), a1);
            a2 = pkfma(rv, f2(w[2][d], w[2][d + 1]), a2);
            a3 = pkfma(rv, f2(w[3][d], w[3][d + 1]), a3);
        }
        const float rl = rr[11];
        float4 ov;
        ov.x = (a0.x + a0.y + rr[10] * w[0][10]) * rl + bv.x;
        ov.y = (a1.x + a1.y + rr[10] * w[1][10]) * rl + bv.y;
        ov.z = (a2.x + a2.y + rr[10] * w[2][10]) * rl + bv.z;
        ov.w = (a3.x + a3.y + rr[10] * w[3][10]) * rl + bv.w;
        *(float4*)(out + (size_t)(t0 + r) * E_DIM + e0) = ov;
    }
}

// ---------------------------------------------------------------------------
extern "C" void kernel_launch(void* const* d_in, const int* in_sizes, int n_in,
                              void* d_out, int out_size, void* d_ws, size_t ws_size,
                              hipStream_t stream) {
    const float* xe = (const float*)d_in[1];
    const float* Wk = (const float*)d_in[2];
    const float* bk = (const float*)d_in[3];
    const float* Wq = (const float*)d_in[4];
    const float* bq = (const float*)d_in[5];
    const float* Wv = (const float*)d_in[6];
    const float* bv = (const float*)d_in[7];
    const float* Wf = (const float*)d_in[8];
    const float* bf = (const float*)d_in[9];
    float* out = (float*)d_out;

    float* qkvF  = (float*)d_ws;                              // [T][QS]
    float* partQ = qkvF + (size_t)T_SEQ * QS;                 // [8][T][QS]
    float* part  = partQ;                                     // overlay: [128][T][12]

    qkv_proj<<<dim3(T_SEQ / QRB, QNEC), 256, 0, stream>>>(xe, Wk, bk, Wq, bq, Wv, bv, partQ);
    reduceQ<<<(T_SEQ * QS / 4) / 256, 256, 0, stream>>>(partQ, qkvF);
    attn<<<2112, 256, 0, stream>>>(qkvF, part);               // 2112 thin blocks
    pass2<<<T_SEQ / TR, 256, 0, stream>>>(part, Wf, bf, out);
}